// Round 11
// baseline (476.272 us; speedup 1.0000x reference)
//
#include <hip/hip_runtime.h>
#include <math.h>

#define BB 1024
#define TT 25
#define LP 10
#define MAXD 11

// conv2/conv3 spike staging: rows 0..24 = spikes, row 25 = zeros
#define XR2 26
#define XC 264            // 256 ch + 8 pad, 16B-aligned rows
#define XSZ2 (XR2 * XC)

// conv1 staging: 160 padded channels + 8 pad
#define IC1 140
#define ICP1 160
#define XC1 168
#define XSZ1 (XR2 * XC1)      // per batch, per split: 26*168 = 4368
#define SS1 (2 * XSZ1)        // per-split stride (2 batches) = 8736

typedef __bf16 bf16x8 __attribute__((ext_vector_type(8)));
typedef float  f32x4  __attribute__((ext_vector_type(4)));

#define MFMA16(A, B, C) __builtin_amdgcn_mfma_f32_16x16x32_bf16((A), (B), (C), 0, 0, 0)

// ---------------------------------------------------------------------------
// Triple-split bf16 DCLS taps: K == Khi + Kmid + Klo EXACTLY (Dekker splits).
// Layout [j][Opad][Ipad]; rows o>=O and cols i>=I are zero.
// ---------------------------------------------------------------------------
__global__ void gen_trip(const float* __restrict__ W,
                         const float* __restrict__ P,
                         const float* __restrict__ SIG,
                         __bf16* __restrict__ Khi, __bf16* __restrict__ Kmid,
                         __bf16* __restrict__ Klo,
                         int O, int Opad, int I, int Ipad) {
    int idx = blockIdx.x * blockDim.x + threadIdx.x;
    if (idx >= Opad * Ipad) return;
    int i = idx % Ipad;
    int o = idx / Ipad;
    if (o >= O || i >= I) {
#pragma unroll
        for (int j = 0; j < MAXD; ++j) {
            size_t ofs = ((size_t)(j * Opad + o)) * Ipad + i;
            Khi[ofs] = (__bf16)0.0f;
            Kmid[ofs] = (__bf16)0.0f;
            Klo[ofs] = (__bf16)0.0f;
        }
        return;
    }
    int widx = o * I + i;
    float w  = W[widx];
    float pc = P[widx] + (float)(MAXD / 2);
    float s  = fabsf(SIG[widx]) + 0.27f;
    float x[MAXD];
    float sum = 0.f;
#pragma unroll
    for (int j = 0; j < MAXD; ++j) {
        float d = ((float)j - pc) / s;
        x[j] = expf(-0.5f * d * d);
        sum += x[j];
    }
    float denom = sum + 1e-7f;
#pragma unroll
    for (int j = 0; j < MAXD; ++j) {
        float kv = w * (x[j] / denom);
        __bf16 h = (__bf16)kv;
        float  r1 = kv - (float)h;
        __bf16 m = (__bf16)r1;
        float  r2 = r1 - (float)m;
        __bf16 l = (__bf16)r2;
        size_t ofs = ((size_t)(j * Opad + o)) * Ipad + i;
        Khi[ofs] = h;
        Kmid[ofs] = m;
        Klo[ofs] = l;
    }
}

// ---------------------------------------------------------------------------
// Layer 1 (MFMA, exact 6-term split): round-9 version, unchanged (passing).
// ---------------------------------------------------------------------------
__global__ __launch_bounds__(512, 2)
void conv1_mfma(const float* __restrict__ xin,     // (B, T, 140)
                const __bf16* __restrict__ Khi,    // [j][256][160]
                const __bf16* __restrict__ Kmid,
                const __bf16* __restrict__ Klo,
                const float* __restrict__ bias,
                const float* __restrict__ gamma,
                const float* __restrict__ beta,
                const float* __restrict__ mean,
                const float* __restrict__ var,
                __bf16* __restrict__ spk1) {
    __shared__ __align__(16) char smem[3 * SS1 * 2];   // 52416 B; ys needs 27648
    __bf16* xs = (__bf16*)smem;                        // [split][bl][26][168]
    float*  ys = (float*)smem;                         // [256][27] per-batch

    const int b0   = blockIdx.x * 2;
    const int tid  = threadIdx.x;
    const int w    = tid >> 6;
    const int lane = tid & 63;
    const int lm   = lane & 15;
    const int quad = lane >> 4;

    {
        uint32_t* xz = (uint32_t*)smem;
        for (int k = tid; k < 3 * SS1 / 2; k += 512) xz[k] = 0u;
    }
    __syncthreads();
#pragma unroll
    for (int bl = 0; bl < 2; ++bl) {
        const float* src = xin + (size_t)(b0 + bl) * (TT * IC1);
        for (int k = tid; k < TT * IC1; k += 512) {
            int t = k / IC1;
            int i = k - t * IC1;
            float x  = src[k];
            __bf16 h = (__bf16)x;
            float r1 = x - (float)h;
            __bf16 m = (__bf16)r1;
            float r2 = r1 - (float)m;
            __bf16 l = (__bf16)r2;
            int ofs = bl * XSZ1 + t * XC1 + i;
            xs[0 * SS1 + ofs] = h;
            xs[1 * SS1 + ofs] = m;
            xs[2 * SS1 + ofs] = l;
        }
    }
    __syncthreads();

    f32x4 acc[2][4];   // [p][bl*2+th]
#pragma unroll
    for (int p = 0; p < 2; ++p)
#pragma unroll
        for (int nt = 0; nt < 4; ++nt) acc[p][nt] = (f32x4){0.f, 0.f, 0.f, 0.f};

    auto loadA = [&](int n, bf16x8* Ah, bf16x8* Am, bf16x8* Al) {
        n = (n > 54) ? 54 : n;
        const int j = n / 5;
        const int ic = n - 5 * j;
        const size_t base =
            (size_t)(j * 256 + w * 32 + lm) * ICP1 + ic * 32 + quad * 8;
#pragma unroll
        for (int p = 0; p < 2; ++p) {
            Ah[p] = *(const bf16x8*)(Khi  + base + p * 16 * ICP1);
            Am[p] = *(const bf16x8*)(Kmid + base + p * 16 * ICP1);
            Al[p] = *(const bf16x8*)(Klo  + base + p * 16 * ICP1);
        }
    };

    auto step = [&](int n, bf16x8* Ah, bf16x8* Am, bf16x8* Al) {
        const int j = n / 5;
        const int ic = n - 5 * j;
        int r0 = lm + j - 10;          r0 = ((unsigned)r0 < 25u) ? r0 : 25;
        int r1 = 16 + lm + j - 10;     r1 = ((unsigned)r1 < 25u) ? r1 : 25;
        const int col = ic * 32 + quad * 8;
#pragma unroll
        for (int bl = 0; bl < 2; ++bl) {
            bf16x8 Bh[2], Bm[2], Bl[2];
#pragma unroll
            for (int th = 0; th < 2; ++th) {
                const int row = th ? r1 : r0;
                const int ofs = bl * XSZ1 + row * XC1 + col;
                Bh[th] = *(const bf16x8*)&xs[0 * SS1 + ofs];
                Bm[th] = *(const bf16x8*)&xs[1 * SS1 + ofs];
                Bl[th] = *(const bf16x8*)&xs[2 * SS1 + ofs];
            }
#pragma unroll
            for (int p = 0; p < 2; ++p)
#pragma unroll
                for (int th = 0; th < 2; ++th)
                    acc[p][bl * 2 + th] = MFMA16(Ah[p], Bh[th], acc[p][bl * 2 + th]);
#pragma unroll
            for (int p = 0; p < 2; ++p)
#pragma unroll
                for (int th = 0; th < 2; ++th)
                    acc[p][bl * 2 + th] = MFMA16(Ah[p], Bm[th], acc[p][bl * 2 + th]);
#pragma unroll
            for (int p = 0; p < 2; ++p)
#pragma unroll
                for (int th = 0; th < 2; ++th)
                    acc[p][bl * 2 + th] = MFMA16(Am[p], Bh[th], acc[p][bl * 2 + th]);
#pragma unroll
            for (int p = 0; p < 2; ++p)
#pragma unroll
                for (int th = 0; th < 2; ++th)
                    acc[p][bl * 2 + th] = MFMA16(Ah[p], Bl[th], acc[p][bl * 2 + th]);
#pragma unroll
            for (int p = 0; p < 2; ++p)
#pragma unroll
                for (int th = 0; th < 2; ++th)
                    acc[p][bl * 2 + th] = MFMA16(Am[p], Bm[th], acc[p][bl * 2 + th]);
#pragma unroll
            for (int p = 0; p < 2; ++p)
#pragma unroll
                for (int th = 0; th < 2; ++th)
                    acc[p][bl * 2 + th] = MFMA16(Al[p], Bh[th], acc[p][bl * 2 + th]);
        }
    };

    bf16x8 A0h[2], A0m[2], A0l[2], A1h[2], A1m[2], A1l[2];
    loadA(0, A0h, A0m, A0l);
    for (int n = 0; n < 54; n += 2) {
        loadA(n + 1, A1h, A1m, A1l);
        step(n, A0h, A0m, A0l);
        loadA(n + 2, A0h, A0m, A0l);
        step(n + 1, A1h, A1m, A1l);
    }
    step(54, A0h, A0m, A0l);

#pragma unroll
    for (int bl = 0; bl < 2; ++bl) {
        __syncthreads();
#pragma unroll
        for (int p = 0; p < 2; ++p)
#pragma unroll
            for (int th = 0; th < 2; ++th) {
                int t = th * 16 + lm;
                if (t < TT) {
                    int ob = w * 32 + p * 16 + quad * 4;
#pragma unroll
                    for (int v = 0; v < 4; ++v)
                        ys[(ob + v) * 27 + t] = acc[p][bl * 2 + th][v];
                }
            }
        __syncthreads();
        if (tid < 256) {
            const int o = tid;
            float scale = gamma[o] / sqrtf(var[o] + 1e-5f);
            float ofs   = (bias[o] - mean[o]) * scale + beta[o];
            unsigned short* dst =
                (unsigned short*)spk1 + (size_t)(b0 + bl) * (TT * 256) + o;
            const float* yrow = &ys[o * 27];
            float memv = 0.f;
#pragma unroll
            for (int t = 0; t < TT; ++t) {
                float a     = yrow[t] * scale + ofs;
                float reset = (memv > 1.0f) ? 1.0f : 0.f;
                memv        = 0.95f * memv + a - reset;
                dst[t * 256] = (memv > 1.0f) ? 0x3F80 : 0;
            }
        }
    }
}

// ---------------------------------------------------------------------------
// Layers 2+3 FUSED, 1024 threads = 16 waves (4 waves/SIMD at 1 block/CU).
// Wave w = one o16-tile, 8 (bl,th) accumulators; per step 3 A-loads feed
// 24 MFMAs. All per-accumulator chains verbatim round-10 => bitwise repro.
// ---------------------------------------------------------------------------
__global__ __launch_bounds__(1024, 4)
void conv23_mfma(const __bf16* __restrict__ spk1,
                 const __bf16* __restrict__ Khi,
                 const __bf16* __restrict__ Kmid,
                 const __bf16* __restrict__ Klo,
                 const float* __restrict__ bias,
                 const float* __restrict__ gamma,
                 const float* __restrict__ beta,
                 const float* __restrict__ mean,
                 const float* __restrict__ var,
                 const __bf16* __restrict__ K3hi,
                 const __bf16* __restrict__ K3mid,
                 const __bf16* __restrict__ K3lo,
                 const float* __restrict__ b3,
                 float* __restrict__ out) {
    __shared__ __align__(16) char smem[61568];
    __bf16* xs  = (__bf16*)smem;                 // [4][26][264] = 54912 B
    float*  ysq = (float*)(smem + 54912);        // [64][26]     = 6656 B
    float*  ys3 = (float*)smem;                  // [4][32][26] alias (conv3)

    const int b0   = blockIdx.x * 4;
    const int tid  = threadIdx.x;
    const int w    = tid >> 6;      // wave 0..15
    const int lane = tid & 63;
    const int lm   = lane & 15;
    const int quad = lane >> 4;

    // zero row 25 of each batch
    for (int k = tid; k < 4 * (XC / 2); k += 1024) {
        int bl = k / (XC / 2);
        int c  = k % (XC / 2);
        ((uint32_t*)xs)[(bl * XSZ2 + 25 * XC) / 2 + c] = 0u;
    }
    // vectorized staging: 8 bf16 per thread-iter
    for (int k = tid; k < 4 * 800; k += 1024) {
        int bl = k / 800;
        int v  = k % 800;            // 800 = 25 rows * 32 vec8
        int t  = v >> 5;
        int iv = v & 31;
        uint4 d = ((const uint4*)(spk1 + (size_t)(b0 + bl) * (TT * 256)))[v];
        *(uint4*)&xs[bl * XSZ2 + t * XC + iv * 8] = d;
    }
    __syncthreads();

    // ---------------- conv2 K-loop (chains identical to r9/r10) ----------
    f32x4 acc[8];   // [bl*2+th]
#pragma unroll
    for (int nt = 0; nt < 8; ++nt) acc[nt] = (f32x4){0.f, 0.f, 0.f, 0.f};

    {
        auto loadA = [&](int n, bf16x8* Ah, bf16x8* Am, bf16x8* Al) {
            n = (n > 87) ? 87 : n;
            const int j = n >> 3, ic = n & 7;
            const size_t base =
                (size_t)(j * 256 + w * 16 + lm) * 256 + ic * 32 + quad * 8;
            *Ah = *(const bf16x8*)(Khi  + base);
            *Am = *(const bf16x8*)(Kmid + base);
            *Al = *(const bf16x8*)(Klo  + base);
        };
        auto loadB = [&](int n, bf16x8* Bf) {
            const int j = n >> 3, ic = n & 7;
            int r0 = lm + j - 10;          r0 = ((unsigned)r0 < 25u) ? r0 : 25;
            int r1 = 16 + lm + j - 10;     r1 = ((unsigned)r1 < 25u) ? r1 : 25;
            const int col = ic * 32 + quad * 8;
#pragma unroll
            for (int bl = 0; bl < 4; ++bl) {
                Bf[bl * 2 + 0] = *(const bf16x8*)&xs[bl * XSZ2 + r0 * XC + col];
                Bf[bl * 2 + 1] = *(const bf16x8*)&xs[bl * XSZ2 + r1 * XC + col];
            }
        };
        auto compute = [&](bf16x8 Ah, bf16x8 Am, bf16x8 Al, bf16x8* Bf) {
#pragma unroll
            for (int nt = 0; nt < 8; ++nt) acc[nt] = MFMA16(Ah, Bf[nt], acc[nt]);
#pragma unroll
            for (int nt = 0; nt < 8; ++nt) acc[nt] = MFMA16(Am, Bf[nt], acc[nt]);
#pragma unroll
            for (int nt = 0; nt < 8; ++nt) acc[nt] = MFMA16(Al, Bf[nt], acc[nt]);
        };

        bf16x8 A0h, A0m, A0l, A1h, A1m, A1l, B0[8], B1[8];
        loadA(0, &A0h, &A0m, &A0l);
        loadB(0, B0);
        for (int n = 0; n < 86; n += 2) {
            loadA(n + 1, &A1h, &A1m, &A1l);
            loadB(n + 1, B1);
            compute(A0h, A0m, A0l, B0);
            loadA(n + 2, &A0h, &A0m, &A0l);
            loadB(n + 2, B0);
            compute(A1h, A1m, A1l, B1);
        }
        loadA(87, &A1h, &A1m, &A1l);
        loadB(87, B1);
        compute(A0h, A0m, A0l, B0);   // n = 86
        compute(A1h, A1m, A1l, B1);   // n = 87
    }

    // ------- conv2 epilogue: BN + LIF, spikes written back into xs -------
#pragma unroll
    for (int bl = 0; bl < 4; ++bl) {
#pragma unroll
        for (int q = 0; q < 4; ++q) {
            __syncthreads();
            if ((w >> 2) == q) {
#pragma unroll
                for (int th = 0; th < 2; ++th) {
                    int t = th * 16 + lm;
                    if (t < TT) {
                        int ol = (w & 3) * 16 + quad * 4;
#pragma unroll
                        for (int v = 0; v < 4; ++v)
                            ysq[(ol + v) * 26 + t] = acc[bl * 2 + th][v];
                    }
                }
            }
            __syncthreads();
            if (tid < 64) {
                const int o = q * 64 + tid;
                float scale = gamma[o] / sqrtf(var[o] + 1e-5f);
                float ofs   = (bias[o] - mean[o]) * scale + beta[o];
                const float* yrow = &ysq[tid * 26];
                unsigned short* sx = (unsigned short*)xs;
                float memv = 0.f;
#pragma unroll
                for (int t = 0; t < TT; ++t) {
                    float a     = yrow[t] * scale + ofs;
                    float reset = (memv > 1.0f) ? 1.0f : 0.f;
                    memv        = 0.95f * memv + a - reset;
                    sx[bl * XSZ2 + t * XC + o] = (memv > 1.0f) ? 0x3F80 : 0;
                }
            }
        }
    }
    __syncthreads();

    // ---------------- conv3 K-loop from LDS (r10 3-acc chains) -----------
    {
        const int p3  = w >> 3;         // o3-tile
        const int bl3 = (w >> 1) & 3;   // batch
        const int th3 = w & 1;          // t half
        f32x4 accH = (f32x4){0.f, 0.f, 0.f, 0.f};
        f32x4 accM = (f32x4){0.f, 0.f, 0.f, 0.f};
        f32x4 accL = (f32x4){0.f, 0.f, 0.f, 0.f};

        auto loadA3 = [&](int n, bf16x8* Ah, bf16x8* Am, bf16x8* Al) {
            n = (n > 87) ? 87 : n;
            const int j = n >> 3, ic = n & 7;
            const size_t kofs =
                ((size_t)(j * 32 + p3 * 16 + lm)) * 256 + ic * 32 + quad * 8;
            *Ah = *(const bf16x8*)(K3hi  + kofs);
            *Am = *(const bf16x8*)(K3mid + kofs);
            *Al = *(const bf16x8*)(K3lo  + kofs);
        };
        auto step3 = [&](int n, bf16x8 Ah, bf16x8 Am, bf16x8 Al) {
            const int j = n >> 3, ic = n & 7;
            int r = th3 * 16 + lm + j - 10;
            r = ((unsigned)r < 25u) ? r : 25;
            bf16x8 Bf =
                *(const bf16x8*)&xs[bl3 * XSZ2 + r * XC + ic * 32 + quad * 8];
            accH = MFMA16(Ah, Bf, accH);
            accM = MFMA16(Am, Bf, accM);
            accL = MFMA16(Al, Bf, accL);
        };

        bf16x8 A0h, A0m, A0l, A1h, A1m, A1l;
        loadA3(0, &A0h, &A0m, &A0l);
        for (int n = 0; n < 86; n += 2) {
            loadA3(n + 1, &A1h, &A1m, &A1l);
            step3(n, A0h, A0m, A0l);
            loadA3(n + 2, &A0h, &A0m, &A0l);
            step3(n + 1, A1h, A1m, A1l);
        }
        loadA3(87, &A1h, &A1m, &A1l);
        step3(86, A0h, A0m, A0l);
        step3(87, A1h, A1m, A1l);

        __syncthreads();   // xs dead; reuse smem as ys3
        {
            int t = th3 * 16 + lm;
            if (t < TT) {
#pragma unroll
                for (int v = 0; v < 4; ++v)
                    ys3[(bl3 * 32 + p3 * 16 + quad * 4 + v) * 26 + t] =
                        accH[v] + accM[v] + accL[v];
            }
        }
        __syncthreads();

        if (tid < 80) {
            const int bl2 = tid / 20;
            const int o   = tid % 20;
            float memv = 0.f;
            float bo   = b3[o];
            const float* yrow = &ys3[(bl2 * 32 + o) * 26];
#pragma unroll
            for (int t = 0; t < TT; ++t) {
                float a     = yrow[t] + bo;
                float reset = (memv > 1.0f) ? 1.0f : 0.f;
                memv        = 0.95f * memv + a - reset;
                float spk   = (memv > 1.0f) ? 1.0f : 0.f;
                out[(t * BB + (b0 + bl2)) * 20 + o]               = spk;
                out[TT * BB * 20 + (t * BB + (b0 + bl2)) * 20 + o] = memv;
            }
        }
    }
}

// ---------------------------------------------------------------------------
extern "C" void kernel_launch(void* const* d_in, const int* in_sizes, int n_in,
                              void* d_out, int out_size, void* d_ws, size_t ws_size,
                              hipStream_t stream) {
    const float* data = (const float*)d_in[0];
    const float* W1   = (const float*)d_in[1];
    const float* b1   = (const float*)d_in[2];
    const float* P1   = (const float*)d_in[3];
    const float* SIG1 = (const float*)d_in[4];
    const float* g1   = (const float*)d_in[5];
    const float* be1  = (const float*)d_in[6];
    const float* m1   = (const float*)d_in[7];
    const float* v1   = (const float*)d_in[8];
    const float* W2   = (const float*)d_in[9];
    const float* b2   = (const float*)d_in[10];
    const float* P2   = (const float*)d_in[11];
    const float* SIG2 = (const float*)d_in[12];
    const float* g2   = (const float*)d_in[13];
    const float* be2  = (const float*)d_in[14];
    const float* m2   = (const float*)d_in[15];
    const float* v2   = (const float*)d_in[16];
    const float* W3   = (const float*)d_in[17];
    const float* b3   = (const float*)d_in[18];
    const float* P3   = (const float*)d_in[19];
    const float* SIG3 = (const float*)d_in[20];
    float* out = (float*)d_out;

    // workspace layout (byte offsets, all 16B-aligned)
    char* p = (char*)d_ws;
    __bf16* K1hi  = (__bf16*)p;  p += 901120;    // 11*256*160 bf16
    __bf16* K1mid = (__bf16*)p;  p += 901120;
    __bf16* K1lo  = (__bf16*)p;  p += 901120;
    __bf16* spk1  = (__bf16*)p;  p += 13107200;  // 1024*25*256 bf16
    __bf16* K2hi  = (__bf16*)p;  p += 1441792;   // 11*256*256 bf16
    __bf16* K2mid = (__bf16*)p;  p += 1441792;
    __bf16* K2lo  = (__bf16*)p;  p += 1441792;
    __bf16* K3hi  = (__bf16*)p;  p += 180224;    // 11*32*256 bf16
    __bf16* K3mid = (__bf16*)p;  p += 180224;
    __bf16* K3lo  = (__bf16*)p;

    gen_trip<<<(256 * 160 + 255) / 256, 256, 0, stream>>>(
        W1, P1, SIG1, K1hi, K1mid, K1lo, 256, 256, 140, 160);
    gen_trip<<<(256 * 256 + 255) / 256, 256, 0, stream>>>(
        W2, P2, SIG2, K2hi, K2mid, K2lo, 256, 256, 256, 256);
    gen_trip<<<(32 * 256 + 255) / 256, 256, 0, stream>>>(
        W3, P3, SIG3, K3hi, K3mid, K3lo, 20, 32, 256, 256);

    conv1_mfma<<<BB / 2, 512, 0, stream>>>(data, K1hi, K1mid, K1lo,
                                           b1, g1, be1, m1, v1, spk1);
    conv23_mfma<<<BB / 4, 1024, 0, stream>>>(spk1, K2hi, K2mid, K2lo,
                                             b2, g2, be2, m2, v2,
                                             K3hi, K3mid, K3lo, b3, out);
}

// Round 12
// 466.325 us; speedup vs baseline: 1.0213x; 1.0213x over previous
//
#include <hip/hip_runtime.h>
#include <math.h>

#define BB 1024
#define TT 25
#define LP 10
#define MAXD 11

// conv2/conv3 spike staging: rows 0..24 = spikes, row 25 = zeros
#define XR2 26
#define XC 264            // 256 ch + 8 pad, 16B-aligned rows
#define XSZ2 (XR2 * XC)

// conv1 fp32 staging: [4][26][144] + 16-float guard
#define IC1 140
#define ICP1 160          // A-operand padded I (zeros for i>=140)
#define XF_ROW 144
#define XF_BATCH (XR2 * XF_ROW)       // 3744 floats
#define XF_TOT (4 * XF_BATCH + 16)    // 14992 floats = 59968 B

typedef __bf16 bf16x8 __attribute__((ext_vector_type(8)));
typedef float  f32x4  __attribute__((ext_vector_type(4)));

#define MFMA16(A, B, C) __builtin_amdgcn_mfma_f32_16x16x32_bf16((A), (B), (C), 0, 0, 0)

// ---------------------------------------------------------------------------
// Triple-split bf16 DCLS taps: K == Khi + Kmid + Klo EXACTLY (Dekker splits).
// Layout [j][Opad][Ipad]; rows o>=O and cols i>=I are zero.
// ---------------------------------------------------------------------------
__global__ void gen_trip(const float* __restrict__ W,
                         const float* __restrict__ P,
                         const float* __restrict__ SIG,
                         __bf16* __restrict__ Khi, __bf16* __restrict__ Kmid,
                         __bf16* __restrict__ Klo,
                         int O, int Opad, int I, int Ipad) {
    int idx = blockIdx.x * blockDim.x + threadIdx.x;
    if (idx >= Opad * Ipad) return;
    int i = idx % Ipad;
    int o = idx / Ipad;
    if (o >= O || i >= I) {
#pragma unroll
        for (int j = 0; j < MAXD; ++j) {
            size_t ofs = ((size_t)(j * Opad + o)) * Ipad + i;
            Khi[ofs] = (__bf16)0.0f;
            Kmid[ofs] = (__bf16)0.0f;
            Klo[ofs] = (__bf16)0.0f;
        }
        return;
    }
    int widx = o * I + i;
    float w  = W[widx];
    float pc = P[widx] + (float)(MAXD / 2);
    float s  = fabsf(SIG[widx]) + 0.27f;
    float x[MAXD];
    float sum = 0.f;
#pragma unroll
    for (int j = 0; j < MAXD; ++j) {
        float d = ((float)j - pc) / s;
        x[j] = expf(-0.5f * d * d);
        sum += x[j];
    }
    float denom = sum + 1e-7f;
#pragma unroll
    for (int j = 0; j < MAXD; ++j) {
        float kv = w * (x[j] / denom);
        __bf16 h = (__bf16)kv;
        float  r1 = kv - (float)h;
        __bf16 m = (__bf16)r1;
        float  r2 = r1 - (float)m;
        __bf16 l = (__bf16)r2;
        size_t ofs = ((size_t)(j * Opad + o)) * Ipad + i;
        Khi[ofs] = h;
        Kmid[ofs] = m;
        Klo[ofs] = l;
    }
}

// ---------------------------------------------------------------------------
// Layer 1 (MFMA, exact 6-term split, 4 batches/block): fp32 x staged raw in
// LDS; Dekker splits computed at load time (VALU pipe overlaps MFMA pipe).
// Wave w = o-range [w*32,w*32+32), acc[2][8] = 16 tiles, 96 MFMAs per
// 6-load A-set. Per-accumulator chains verbatim round-9 => bitwise repro.
// ---------------------------------------------------------------------------
__global__ __launch_bounds__(512, 2)
void conv1_mfma(const float* __restrict__ xin,     // (B, T, 140)
                const __bf16* __restrict__ Khi,    // [j][256][160]
                const __bf16* __restrict__ Kmid,
                const __bf16* __restrict__ Klo,
                const float* __restrict__ bias,
                const float* __restrict__ gamma,
                const float* __restrict__ beta,
                const float* __restrict__ mean,
                const float* __restrict__ var,
                __bf16* __restrict__ spk1) {
    __shared__ __align__(16) char smem[XF_TOT * 4];    // 59968 B
    float* xsf = (float*)smem;                         // [4][26][144] + guard
    float* ys  = (float*)smem;                         // [256][27] per-batch alias

    const int b0   = blockIdx.x * 4;
    const int tid  = threadIdx.x;
    const int w    = tid >> 6;
    const int lane = tid & 63;
    const int lm   = lane & 15;
    const int quad = lane >> 4;

    for (int k = tid; k < XF_TOT; k += 512) xsf[k] = 0.f;
    __syncthreads();
#pragma unroll
    for (int bl = 0; bl < 4; ++bl) {
        const float* src = xin + (size_t)(b0 + bl) * (TT * IC1);
        for (int k = tid; k < TT * IC1; k += 512) {
            int t = k / IC1;
            int i = k - t * IC1;
            xsf[bl * XF_BATCH + t * XF_ROW + i] = src[k];
        }
    }
    __syncthreads();

    f32x4 acc[2][8];   // [p][bl*2+th]
#pragma unroll
    for (int p = 0; p < 2; ++p)
#pragma unroll
        for (int nt = 0; nt < 8; ++nt) acc[p][nt] = (f32x4){0.f, 0.f, 0.f, 0.f};

    auto loadA = [&](int n, bf16x8* Ah, bf16x8* Am, bf16x8* Al) {
        n = (n > 54) ? 54 : n;
        const int j = n / 5;
        const int ic = n - 5 * j;
        const size_t base =
            (size_t)(j * 256 + w * 32 + lm) * ICP1 + ic * 32 + quad * 8;
#pragma unroll
        for (int p = 0; p < 2; ++p) {
            Ah[p] = *(const bf16x8*)(Khi  + base + p * 16 * ICP1);
            Am[p] = *(const bf16x8*)(Kmid + base + p * 16 * ICP1);
            Al[p] = *(const bf16x8*)(Klo  + base + p * 16 * ICP1);
        }
    };

    auto step = [&](int n, bf16x8* Ah, bf16x8* Am, bf16x8* Al) {
        const int j = n / 5;
        const int ic = n - 5 * j;
        int r0 = lm + j - 10;          r0 = ((unsigned)r0 < 25u) ? r0 : 25;
        int r1 = 16 + lm + j - 10;     r1 = ((unsigned)r1 < 25u) ? r1 : 25;
        const int col = ic * 32 + quad * 8;
#pragma unroll
        for (int bl = 0; bl < 4; ++bl) {
            bf16x8 Bh[2], Bm[2], Bl[2];
#pragma unroll
            for (int th = 0; th < 2; ++th) {
                const int row = th ? r1 : r0;
                const float* bp = &xsf[bl * XF_BATCH + row * XF_ROW + col];
                float xv[8];
                *(float4*)&xv[0] = *(const float4*)bp;
                *(float4*)&xv[4] = *(const float4*)(bp + 4);
#pragma unroll
                for (int e = 0; e < 8; ++e) {
                    __bf16 h = (__bf16)xv[e];
                    float  q1 = xv[e] - (float)h;
                    __bf16 m = (__bf16)q1;
                    float  q2 = q1 - (float)m;
                    Bh[th][e] = h;
                    Bm[th][e] = m;
                    Bl[th][e] = (__bf16)q2;
                }
            }
            // round-9 6-term product order per accumulator (bitwise repro)
#pragma unroll
            for (int p = 0; p < 2; ++p)
#pragma unroll
                for (int th = 0; th < 2; ++th)
                    acc[p][bl * 2 + th] = MFMA16(Ah[p], Bh[th], acc[p][bl * 2 + th]);
#pragma unroll
            for (int p = 0; p < 2; ++p)
#pragma unroll
                for (int th = 0; th < 2; ++th)
                    acc[p][bl * 2 + th] = MFMA16(Ah[p], Bm[th], acc[p][bl * 2 + th]);
#pragma unroll
            for (int p = 0; p < 2; ++p)
#pragma unroll
                for (int th = 0; th < 2; ++th)
                    acc[p][bl * 2 + th] = MFMA16(Am[p], Bh[th], acc[p][bl * 2 + th]);
#pragma unroll
            for (int p = 0; p < 2; ++p)
#pragma unroll
                for (int th = 0; th < 2; ++th)
                    acc[p][bl * 2 + th] = MFMA16(Ah[p], Bl[th], acc[p][bl * 2 + th]);
#pragma unroll
            for (int p = 0; p < 2; ++p)
#pragma unroll
                for (int th = 0; th < 2; ++th)
                    acc[p][bl * 2 + th] = MFMA16(Am[p], Bm[th], acc[p][bl * 2 + th]);
#pragma unroll
            for (int p = 0; p < 2; ++p)
#pragma unroll
                for (int th = 0; th < 2; ++th)
                    acc[p][bl * 2 + th] = MFMA16(Al[p], Bh[th], acc[p][bl * 2 + th]);
        }
    };

    bf16x8 A0h[2], A0m[2], A0l[2], A1h[2], A1m[2], A1l[2];
    loadA(0, A0h, A0m, A0l);
    for (int n = 0; n < 54; n += 2) {
        loadA(n + 1, A1h, A1m, A1l);
        step(n, A0h, A0m, A0l);
        loadA(n + 2, A0h, A0m, A0l);
        step(n + 1, A1h, A1m, A1l);
    }
    step(54, A0h, A0m, A0l);

    // epilogue: per batch through LDS (xsf dead), then BN + LIF
#pragma unroll
    for (int bl = 0; bl < 4; ++bl) {
        __syncthreads();
#pragma unroll
        for (int p = 0; p < 2; ++p)
#pragma unroll
            for (int th = 0; th < 2; ++th) {
                int t = th * 16 + lm;
                if (t < TT) {
                    int ob = w * 32 + p * 16 + quad * 4;
#pragma unroll
                    for (int v = 0; v < 4; ++v)
                        ys[(ob + v) * 27 + t] = acc[p][bl * 2 + th][v];
                }
            }
        __syncthreads();
        if (tid < 256) {
            const int o = tid;
            float scale = gamma[o] / sqrtf(var[o] + 1e-5f);
            float ofs   = (bias[o] - mean[o]) * scale + beta[o];
            unsigned short* dst =
                (unsigned short*)spk1 + (size_t)(b0 + bl) * (TT * 256) + o;
            const float* yrow = &ys[o * 27];
            float memv = 0.f;
#pragma unroll
            for (int t = 0; t < TT; ++t) {
                float a     = yrow[t] * scale + ofs;
                float reset = (memv > 1.0f) ? 1.0f : 0.f;
                memv        = 0.95f * memv + a - reset;
                dst[t * 256] = (memv > 1.0f) ? 0x3F80 : 0;
            }
        }
    }
}

// ---------------------------------------------------------------------------
// Layers 2+3 FUSED: round-10 version, verbatim (best measured: 255 us).
// ---------------------------------------------------------------------------
__global__ __launch_bounds__(512, 2)
void conv23_mfma(const __bf16* __restrict__ spk1,
                 const __bf16* __restrict__ Khi,
                 const __bf16* __restrict__ Kmid,
                 const __bf16* __restrict__ Klo,
                 const float* __restrict__ bias,
                 const float* __restrict__ gamma,
                 const float* __restrict__ beta,
                 const float* __restrict__ mean,
                 const float* __restrict__ var,
                 const __bf16* __restrict__ K3hi,
                 const __bf16* __restrict__ K3mid,
                 const __bf16* __restrict__ K3lo,
                 const float* __restrict__ b3,
                 float* __restrict__ out) {
    __shared__ __align__(16) char smem[61568];
    __bf16* xs  = (__bf16*)smem;                 // [4][26][264] = 54912 B
    float*  ysq = (float*)(smem + 54912);        // [64][26]     = 6656 B
    float*  ys3 = (float*)smem;                  // [4][32][26] alias (conv3)

    const int b0   = blockIdx.x * 4;
    const int tid  = threadIdx.x;
    const int w    = tid >> 6;
    const int lane = tid & 63;
    const int lm   = lane & 15;
    const int quad = lane >> 4;

    for (int k = tid; k < 4 * (XC / 2); k += 512) {
        int bl = k / (XC / 2);
        int c  = k % (XC / 2);
        ((uint32_t*)xs)[(bl * XSZ2 + 25 * XC) / 2 + c] = 0u;
    }
    for (int k = tid; k < 4 * 800; k += 512) {
        int bl = k / 800;
        int v  = k % 800;
        int t  = v >> 5;
        int iv = v & 31;
        uint4 d = ((const uint4*)(spk1 + (size_t)(b0 + bl) * (TT * 256)))[v];
        *(uint4*)&xs[bl * XSZ2 + t * XC + iv * 8] = d;
    }
    __syncthreads();

    f32x4 acc[2][8];   // [pi][bl*2+th]
#pragma unroll
    for (int pi = 0; pi < 2; ++pi)
#pragma unroll
        for (int nt = 0; nt < 8; ++nt) acc[pi][nt] = (f32x4){0.f, 0.f, 0.f, 0.f};

    {
        auto loadA = [&](int n, bf16x8* Ah, bf16x8* Am, bf16x8* Al) {
            n = (n > 87) ? 87 : n;
            const int j = n >> 3, ic = n & 7;
#pragma unroll
            for (int pi = 0; pi < 2; ++pi) {
                const size_t base =
                    (size_t)(j * 256 + w * 32 + pi * 16 + lm) * 256 + ic * 32 + quad * 8;
                Ah[pi] = *(const bf16x8*)(Khi  + base);
                Am[pi] = *(const bf16x8*)(Kmid + base);
                Al[pi] = *(const bf16x8*)(Klo  + base);
            }
        };
        auto loadB = [&](int n, bf16x8* Bf) {
            const int j = n >> 3, ic = n & 7;
            int r0 = lm + j - 10;          r0 = ((unsigned)r0 < 25u) ? r0 : 25;
            int r1 = 16 + lm + j - 10;     r1 = ((unsigned)r1 < 25u) ? r1 : 25;
            const int col = ic * 32 + quad * 8;
#pragma unroll
            for (int bl = 0; bl < 4; ++bl) {
                Bf[bl * 2 + 0] = *(const bf16x8*)&xs[bl * XSZ2 + r0 * XC + col];
                Bf[bl * 2 + 1] = *(const bf16x8*)&xs[bl * XSZ2 + r1 * XC + col];
            }
        };
        auto compute = [&](bf16x8* Ah, bf16x8* Am, bf16x8* Al, bf16x8* Bf) {
#pragma unroll
            for (int pi = 0; pi < 2; ++pi)
#pragma unroll
                for (int nt = 0; nt < 8; ++nt)
                    acc[pi][nt] = MFMA16(Ah[pi], Bf[nt], acc[pi][nt]);
#pragma unroll
            for (int pi = 0; pi < 2; ++pi)
#pragma unroll
                for (int nt = 0; nt < 8; ++nt)
                    acc[pi][nt] = MFMA16(Am[pi], Bf[nt], acc[pi][nt]);
#pragma unroll
            for (int pi = 0; pi < 2; ++pi)
#pragma unroll
                for (int nt = 0; nt < 8; ++nt)
                    acc[pi][nt] = MFMA16(Al[pi], Bf[nt], acc[pi][nt]);
        };

        bf16x8 A0h[2], A0m[2], A0l[2], A1h[2], A1m[2], A1l[2], B0[8], B1[8];
        loadA(0, A0h, A0m, A0l);
        loadB(0, B0);
        for (int n = 0; n < 86; n += 2) {
            loadA(n + 1, A1h, A1m, A1l);
            loadB(n + 1, B1);
            compute(A0h, A0m, A0l, B0);
            loadA(n + 2, A0h, A0m, A0l);
            loadB(n + 2, B0);
            compute(A1h, A1m, A1l, B1);
        }
        loadA(87, A1h, A1m, A1l);
        loadB(87, B1);
        compute(A0h, A0m, A0l, B0);   // n = 86
        compute(A1h, A1m, A1l, B1);   // n = 87
    }

    // ------- conv2 epilogue: BN + LIF, spikes written back into xs -------
#pragma unroll
    for (int bl = 0; bl < 4; ++bl) {
#pragma unroll
        for (int q = 0; q < 4; ++q) {
            __syncthreads();
            if ((w >> 1) == q) {
#pragma unroll
                for (int pi = 0; pi < 2; ++pi)
#pragma unroll
                    for (int th = 0; th < 2; ++th) {
                        int t = th * 16 + lm;
                        if (t < TT) {
                            int ol = (w & 1) * 32 + pi * 16 + quad * 4;
#pragma unroll
                            for (int v = 0; v < 4; ++v)
                                ysq[(ol + v) * 26 + t] = acc[pi][bl * 2 + th][v];
                        }
                    }
            }
            __syncthreads();
            if (tid < 64) {
                const int o = q * 64 + tid;
                float scale = gamma[o] / sqrtf(var[o] + 1e-5f);
                float ofs   = (bias[o] - mean[o]) * scale + beta[o];
                const float* yrow = &ysq[tid * 26];
                unsigned short* sx = (unsigned short*)xs;
                float memv = 0.f;
#pragma unroll
                for (int t = 0; t < TT; ++t) {
                    float a     = yrow[t] * scale + ofs;
                    float reset = (memv > 1.0f) ? 1.0f : 0.f;
                    memv        = 0.95f * memv + a - reset;
                    sx[bl * XSZ2 + t * XC + o] = (memv > 1.0f) ? 0x3F80 : 0;
                }
            }
        }
    }
    __syncthreads();

    // ---------------- conv3 K-loop from LDS (round-9/10 3-acc order) -----
    {
        const int p3  = w >> 2;      // o3-tile
        const int bl3 = w & 3;       // batch
        f32x4 accH[2], accM[2], accL[2];   // [th]
#pragma unroll
        for (int th = 0; th < 2; ++th) {
            accH[th] = (f32x4){0.f, 0.f, 0.f, 0.f};
            accM[th] = (f32x4){0.f, 0.f, 0.f, 0.f};
            accL[th] = (f32x4){0.f, 0.f, 0.f, 0.f};
        }

        auto loadA3 = [&](int n, bf16x8* Ah, bf16x8* Am, bf16x8* Al) {
            n = (n > 87) ? 87 : n;
            const int j = n >> 3, ic = n & 7;
            const size_t kofs =
                ((size_t)(j * 32 + p3 * 16 + lm)) * 256 + ic * 32 + quad * 8;
            *Ah = *(const bf16x8*)(K3hi  + kofs);
            *Am = *(const bf16x8*)(K3mid + kofs);
            *Al = *(const bf16x8*)(K3lo  + kofs);
        };
        auto step3 = [&](int n, bf16x8 Ah, bf16x8 Am, bf16x8 Al) {
            const int j = n >> 3, ic = n & 7;
#pragma unroll
            for (int th = 0; th < 2; ++th) {
                int r = th * 16 + lm + j - 10;
                r = ((unsigned)r < 25u) ? r : 25;
                bf16x8 Bf =
                    *(const bf16x8*)&xs[bl3 * XSZ2 + r * XC + ic * 32 + quad * 8];
                accH[th] = MFMA16(Ah, Bf, accH[th]);
                accM[th] = MFMA16(Am, Bf, accM[th]);
                accL[th] = MFMA16(Al, Bf, accL[th]);
            }
        };

        bf16x8 A0h, A0m, A0l, A1h, A1m, A1l;
        loadA3(0, &A0h, &A0m, &A0l);
        for (int n = 0; n < 86; n += 2) {
            loadA3(n + 1, &A1h, &A1m, &A1l);
            step3(n, A0h, A0m, A0l);
            loadA3(n + 2, &A0h, &A0m, &A0l);
            step3(n + 1, A1h, A1m, A1l);
        }
        loadA3(87, &A1h, &A1m, &A1l);
        step3(86, A0h, A0m, A0l);
        step3(87, A1h, A1m, A1l);

        __syncthreads();   // xs dead; reuse smem as ys3
#pragma unroll
        for (int th = 0; th < 2; ++th) {
            int t = th * 16 + lm;
            if (t < TT) {
#pragma unroll
                for (int v = 0; v < 4; ++v)
                    ys3[(bl3 * 32 + p3 * 16 + quad * 4 + v) * 26 + t] =
                        accH[th][v] + accM[th][v] + accL[th][v];
            }
        }
        __syncthreads();

        if (tid < 80) {
            const int bl2 = tid / 20;
            const int o   = tid % 20;
            float memv = 0.f;
            float bo   = b3[o];
            const float* yrow = &ys3[(bl2 * 32 + o) * 26];
#pragma unroll
            for (int t = 0; t < TT; ++t) {
                float a     = yrow[t] + bo;
                float reset = (memv > 1.0f) ? 1.0f : 0.f;
                memv        = 0.95f * memv + a - reset;
                float spk   = (memv > 1.0f) ? 1.0f : 0.f;
                out[(t * BB + (b0 + bl2)) * 20 + o]               = spk;
                out[TT * BB * 20 + (t * BB + (b0 + bl2)) * 20 + o] = memv;
            }
        }
    }
}

// ---------------------------------------------------------------------------
extern "C" void kernel_launch(void* const* d_in, const int* in_sizes, int n_in,
                              void* d_out, int out_size, void* d_ws, size_t ws_size,
                              hipStream_t stream) {
    const float* data = (const float*)d_in[0];
    const float* W1   = (const float*)d_in[1];
    const float* b1   = (const float*)d_in[2];
    const float* P1   = (const float*)d_in[3];
    const float* SIG1 = (const float*)d_in[4];
    const float* g1   = (const float*)d_in[5];
    const float* be1  = (const float*)d_in[6];
    const float* m1   = (const float*)d_in[7];
    const float* v1   = (const float*)d_in[8];
    const float* W2   = (const float*)d_in[9];
    const float* b2   = (const float*)d_in[10];
    const float* P2   = (const float*)d_in[11];
    const float* SIG2 = (const float*)d_in[12];
    const float* g2   = (const float*)d_in[13];
    const float* be2  = (const float*)d_in[14];
    const float* m2   = (const float*)d_in[15];
    const float* v2   = (const float*)d_in[16];
    const float* W3   = (const float*)d_in[17];
    const float* b3   = (const float*)d_in[18];
    const float* P3   = (const float*)d_in[19];
    const float* SIG3 = (const float*)d_in[20];
    float* out = (float*)d_out;

    // workspace layout (byte offsets, all 16B-aligned)
    char* p = (char*)d_ws;
    __bf16* K1hi  = (__bf16*)p;  p += 901120;    // 11*256*160 bf16
    __bf16* K1mid = (__bf16*)p;  p += 901120;
    __bf16* K1lo  = (__bf16*)p;  p += 901120;
    __bf16* spk1  = (__bf16*)p;  p += 13107200;  // 1024*25*256 bf16
    __bf16* K2hi  = (__bf16*)p;  p += 1441792;   // 11*256*256 bf16
    __bf16* K2mid = (__bf16*)p;  p += 1441792;
    __bf16* K2lo  = (__bf16*)p;  p += 1441792;
    __bf16* K3hi  = (__bf16*)p;  p += 180224;    // 11*32*256 bf16
    __bf16* K3mid = (__bf16*)p;  p += 180224;
    __bf16* K3lo  = (__bf16*)p;

    gen_trip<<<(256 * 160 + 255) / 256, 256, 0, stream>>>(
        W1, P1, SIG1, K1hi, K1mid, K1lo, 256, 256, 140, 160);
    gen_trip<<<(256 * 256 + 255) / 256, 256, 0, stream>>>(
        W2, P2, SIG2, K2hi, K2mid, K2lo, 256, 256, 256, 256);
    gen_trip<<<(32 * 256 + 255) / 256, 256, 0, stream>>>(
        W3, P3, SIG3, K3hi, K3mid, K3lo, 20, 32, 256, 256);

    conv1_mfma<<<BB / 4, 512, 0, stream>>>(data, K1hi, K1mid, K1lo,
                                           b1, g1, be1, m1, v1, spk1);
    conv23_mfma<<<BB / 4, 512, 0, stream>>>(spk1, K2hi, K2mid, K2lo,
                                            b2, g2, be2, m2, v2,
                                            K3hi, K3mid, K3lo, b3, out);
}

// Round 13
// 424.571 us; speedup vs baseline: 1.1218x; 1.0983x over previous
//
#include <hip/hip_runtime.h>
#include <math.h>

#define BB 1024
#define TT 25
#define LP 10
#define MAXD 11

// conv2/conv3 spike staging: rows 0..24 = spikes, row 25 = zeros
#define XR2 26
#define XC 264            // 256 ch + 8 pad, 16B-aligned rows
#define XSZ2 (XR2 * XC)

// conv1 staging: 160 padded channels + 8 pad
#define IC1 140
#define ICP1 160
#define XC1 168
#define XSZ1 (XR2 * XC1)      // per batch, per split: 26*168 = 4368
#define SS1 (2 * XSZ1)        // per-split stride (2 batches) = 8736

typedef __bf16 bf16x8 __attribute__((ext_vector_type(8)));
typedef float  f32x4  __attribute__((ext_vector_type(4)));

#define MFMA16(A, B, C) __builtin_amdgcn_mfma_f32_16x16x32_bf16((A), (B), (C), 0, 0, 0)

// ---------------------------------------------------------------------------
// Triple-split bf16 DCLS taps: K == Khi + Kmid + Klo EXACTLY (Dekker splits).
// Layout [j][Opad][Ipad]; rows o>=O and cols i>=I are zero.
// ---------------------------------------------------------------------------
__global__ void gen_trip(const float* __restrict__ W,
                         const float* __restrict__ P,
                         const float* __restrict__ SIG,
                         __bf16* __restrict__ Khi, __bf16* __restrict__ Kmid,
                         __bf16* __restrict__ Klo,
                         int O, int Opad, int I, int Ipad) {
    int idx = blockIdx.x * blockDim.x + threadIdx.x;
    if (idx >= Opad * Ipad) return;
    int i = idx % Ipad;
    int o = idx / Ipad;
    if (o >= O || i >= I) {
#pragma unroll
        for (int j = 0; j < MAXD; ++j) {
            size_t ofs = ((size_t)(j * Opad + o)) * Ipad + i;
            Khi[ofs] = (__bf16)0.0f;
            Kmid[ofs] = (__bf16)0.0f;
            Klo[ofs] = (__bf16)0.0f;
        }
        return;
    }
    int widx = o * I + i;
    float w  = W[widx];
    float pc = P[widx] + (float)(MAXD / 2);
    float s  = fabsf(SIG[widx]) + 0.27f;
    float x[MAXD];
    float sum = 0.f;
#pragma unroll
    for (int j = 0; j < MAXD; ++j) {
        float d = ((float)j - pc) / s;
        x[j] = expf(-0.5f * d * d);
        sum += x[j];
    }
    float denom = sum + 1e-7f;
#pragma unroll
    for (int j = 0; j < MAXD; ++j) {
        float kv = w * (x[j] / denom);
        __bf16 h = (__bf16)kv;
        float  r1 = kv - (float)h;
        __bf16 m = (__bf16)r1;
        float  r2 = r1 - (float)m;
        __bf16 l = (__bf16)r2;
        size_t ofs = ((size_t)(j * Opad + o)) * Ipad + i;
        Khi[ofs] = h;
        Kmid[ofs] = m;
        Klo[ofs] = l;
    }
}

// ---------------------------------------------------------------------------
// Layer 1 (MFMA, exact 6-term split): r9 2-batch form (best measured ~150us)
// with XCD-aligned batch-pair swizzle: both writer blocks of conv23-block-i's
// batches land on XCD i%8, so spk1 is L2-local for the consumer.
// ---------------------------------------------------------------------------
__global__ __launch_bounds__(512, 2)
void conv1_mfma(const float* __restrict__ xin,     // (B, T, 140)
                const __bf16* __restrict__ Khi,    // [j][256][160]
                const __bf16* __restrict__ Kmid,
                const __bf16* __restrict__ Klo,
                const float* __restrict__ bias,
                const float* __restrict__ gamma,
                const float* __restrict__ beta,
                const float* __restrict__ mean,
                const float* __restrict__ var,
                __bf16* __restrict__ spk1) {
    __shared__ __align__(16) char smem[3 * SS1 * 2];   // 52416 B; ys needs 27648
    __bf16* xs = (__bf16*)smem;                        // [split][bl][26][168]
    float*  ys = (float*)smem;                         // [256][27] per-batch

    // XCD-aligned batch-pair swizzle (bijection over [0,512)):
    // pair p = 2*(r + 8*(g>>1)) + (g&1); writers of pairs {2i,2i+1} both have
    // blockIdx ≡ i (mod 8) == consumer conv23-block-i's XCD.
    const int rr = blockIdx.x & 7;
    const int gg = blockIdx.x >> 3;
    const int pp = 2 * (rr + 8 * (gg >> 1)) + (gg & 1);
    const int b0 = pp * 2;

    const int tid  = threadIdx.x;
    const int w    = tid >> 6;
    const int lane = tid & 63;
    const int lm   = lane & 15;
    const int quad = lane >> 4;

    {
        uint32_t* xz = (uint32_t*)smem;
        for (int k = tid; k < 3 * SS1 / 2; k += 512) xz[k] = 0u;
    }
    __syncthreads();
#pragma unroll
    for (int bl = 0; bl < 2; ++bl) {
        const float* src = xin + (size_t)(b0 + bl) * (TT * IC1);
        for (int k = tid; k < TT * IC1; k += 512) {
            int t = k / IC1;
            int i = k - t * IC1;
            float x  = src[k];
            __bf16 h = (__bf16)x;
            float r1 = x - (float)h;
            __bf16 m = (__bf16)r1;
            float r2 = r1 - (float)m;
            __bf16 l = (__bf16)r2;
            int ofs = bl * XSZ1 + t * XC1 + i;
            xs[0 * SS1 + ofs] = h;
            xs[1 * SS1 + ofs] = m;
            xs[2 * SS1 + ofs] = l;
        }
    }
    __syncthreads();

    f32x4 acc[2][4];   // [p][bl*2+th]
#pragma unroll
    for (int p = 0; p < 2; ++p)
#pragma unroll
        for (int nt = 0; nt < 4; ++nt) acc[p][nt] = (f32x4){0.f, 0.f, 0.f, 0.f};

    auto loadA = [&](int n, bf16x8* Ah, bf16x8* Am, bf16x8* Al) {
        n = (n > 54) ? 54 : n;
        const int j = n / 5;
        const int ic = n - 5 * j;
        const size_t base =
            (size_t)(j * 256 + w * 32 + lm) * ICP1 + ic * 32 + quad * 8;
#pragma unroll
        for (int p = 0; p < 2; ++p) {
            Ah[p] = *(const bf16x8*)(Khi  + base + p * 16 * ICP1);
            Am[p] = *(const bf16x8*)(Kmid + base + p * 16 * ICP1);
            Al[p] = *(const bf16x8*)(Klo  + base + p * 16 * ICP1);
        }
    };

    auto step = [&](int n, bf16x8* Ah, bf16x8* Am, bf16x8* Al) {
        const int j = n / 5;
        const int ic = n - 5 * j;
        int r0 = lm + j - 10;          r0 = ((unsigned)r0 < 25u) ? r0 : 25;
        int r1 = 16 + lm + j - 10;     r1 = ((unsigned)r1 < 25u) ? r1 : 25;
        const int col = ic * 32 + quad * 8;
#pragma unroll
        for (int bl = 0; bl < 2; ++bl) {
            bf16x8 Bh[2], Bm[2], Bl[2];
#pragma unroll
            for (int th = 0; th < 2; ++th) {
                const int row = th ? r1 : r0;
                const int ofs = bl * XSZ1 + row * XC1 + col;
                Bh[th] = *(const bf16x8*)&xs[0 * SS1 + ofs];
                Bm[th] = *(const bf16x8*)&xs[1 * SS1 + ofs];
                Bl[th] = *(const bf16x8*)&xs[2 * SS1 + ofs];
            }
#pragma unroll
            for (int p = 0; p < 2; ++p)
#pragma unroll
                for (int th = 0; th < 2; ++th)
                    acc[p][bl * 2 + th] = MFMA16(Ah[p], Bh[th], acc[p][bl * 2 + th]);
#pragma unroll
            for (int p = 0; p < 2; ++p)
#pragma unroll
                for (int th = 0; th < 2; ++th)
                    acc[p][bl * 2 + th] = MFMA16(Ah[p], Bm[th], acc[p][bl * 2 + th]);
#pragma unroll
            for (int p = 0; p < 2; ++p)
#pragma unroll
                for (int th = 0; th < 2; ++th)
                    acc[p][bl * 2 + th] = MFMA16(Am[p], Bh[th], acc[p][bl * 2 + th]);
#pragma unroll
            for (int p = 0; p < 2; ++p)
#pragma unroll
                for (int th = 0; th < 2; ++th)
                    acc[p][bl * 2 + th] = MFMA16(Ah[p], Bl[th], acc[p][bl * 2 + th]);
#pragma unroll
            for (int p = 0; p < 2; ++p)
#pragma unroll
                for (int th = 0; th < 2; ++th)
                    acc[p][bl * 2 + th] = MFMA16(Am[p], Bm[th], acc[p][bl * 2 + th]);
#pragma unroll
            for (int p = 0; p < 2; ++p)
#pragma unroll
                for (int th = 0; th < 2; ++th)
                    acc[p][bl * 2 + th] = MFMA16(Al[p], Bh[th], acc[p][bl * 2 + th]);
        }
    };

    bf16x8 A0h[2], A0m[2], A0l[2], A1h[2], A1m[2], A1l[2];
    loadA(0, A0h, A0m, A0l);
    for (int n = 0; n < 54; n += 2) {
        loadA(n + 1, A1h, A1m, A1l);
        step(n, A0h, A0m, A0l);
        loadA(n + 2, A0h, A0m, A0l);
        step(n + 1, A1h, A1m, A1l);
    }
    step(54, A0h, A0m, A0l);

#pragma unroll
    for (int bl = 0; bl < 2; ++bl) {
        __syncthreads();
#pragma unroll
        for (int p = 0; p < 2; ++p)
#pragma unroll
            for (int th = 0; th < 2; ++th) {
                int t = th * 16 + lm;
                if (t < TT) {
                    int ob = w * 32 + p * 16 + quad * 4;
#pragma unroll
                    for (int v = 0; v < 4; ++v)
                        ys[(ob + v) * 27 + t] = acc[p][bl * 2 + th][v];
                }
            }
        __syncthreads();
        if (tid < 256) {
            const int o = tid;
            float scale = gamma[o] / sqrtf(var[o] + 1e-5f);
            float ofs   = (bias[o] - mean[o]) * scale + beta[o];
            unsigned short* dst =
                (unsigned short*)spk1 + (size_t)(b0 + bl) * (TT * 256) + o;
            const float* yrow = &ys[o * 27];
            float memv = 0.f;
#pragma unroll
            for (int t = 0; t < TT; ++t) {
                float a     = yrow[t] * scale + ofs;
                float reset = (memv > 1.0f) ? 1.0f : 0.f;
                memv        = 0.95f * memv + a - reset;
                dst[t * 256] = (memv > 1.0f) ? 0x3F80 : 0;
            }
        }
    }
}

// ---------------------------------------------------------------------------
// Layers 2+3 FUSED: round-10/12 version, verbatim (best measured: 218 us).
// ---------------------------------------------------------------------------
__global__ __launch_bounds__(512, 2)
void conv23_mfma(const __bf16* __restrict__ spk1,
                 const __bf16* __restrict__ Khi,
                 const __bf16* __restrict__ Kmid,
                 const __bf16* __restrict__ Klo,
                 const float* __restrict__ bias,
                 const float* __restrict__ gamma,
                 const float* __restrict__ beta,
                 const float* __restrict__ mean,
                 const float* __restrict__ var,
                 const __bf16* __restrict__ K3hi,
                 const __bf16* __restrict__ K3mid,
                 const __bf16* __restrict__ K3lo,
                 const float* __restrict__ b3,
                 float* __restrict__ out) {
    __shared__ __align__(16) char smem[61568];
    __bf16* xs  = (__bf16*)smem;                 // [4][26][264] = 54912 B
    float*  ysq = (float*)(smem + 54912);        // [64][26]     = 6656 B
    float*  ys3 = (float*)smem;                  // [4][32][26] alias (conv3)

    const int b0   = blockIdx.x * 4;
    const int tid  = threadIdx.x;
    const int w    = tid >> 6;
    const int lane = tid & 63;
    const int lm   = lane & 15;
    const int quad = lane >> 4;

    for (int k = tid; k < 4 * (XC / 2); k += 512) {
        int bl = k / (XC / 2);
        int c  = k % (XC / 2);
        ((uint32_t*)xs)[(bl * XSZ2 + 25 * XC) / 2 + c] = 0u;
    }
    for (int k = tid; k < 4 * 800; k += 512) {
        int bl = k / 800;
        int v  = k % 800;
        int t  = v >> 5;
        int iv = v & 31;
        uint4 d = ((const uint4*)(spk1 + (size_t)(b0 + bl) * (TT * 256)))[v];
        *(uint4*)&xs[bl * XSZ2 + t * XC + iv * 8] = d;
    }
    __syncthreads();

    f32x4 acc[2][8];   // [pi][bl*2+th]
#pragma unroll
    for (int pi = 0; pi < 2; ++pi)
#pragma unroll
        for (int nt = 0; nt < 8; ++nt) acc[pi][nt] = (f32x4){0.f, 0.f, 0.f, 0.f};

    {
        auto loadA = [&](int n, bf16x8* Ah, bf16x8* Am, bf16x8* Al) {
            n = (n > 87) ? 87 : n;
            const int j = n >> 3, ic = n & 7;
#pragma unroll
            for (int pi = 0; pi < 2; ++pi) {
                const size_t base =
                    (size_t)(j * 256 + w * 32 + pi * 16 + lm) * 256 + ic * 32 + quad * 8;
                Ah[pi] = *(const bf16x8*)(Khi  + base);
                Am[pi] = *(const bf16x8*)(Kmid + base);
                Al[pi] = *(const bf16x8*)(Klo  + base);
            }
        };
        auto loadB = [&](int n, bf16x8* Bf) {
            const int j = n >> 3, ic = n & 7;
            int r0 = lm + j - 10;          r0 = ((unsigned)r0 < 25u) ? r0 : 25;
            int r1 = 16 + lm + j - 10;     r1 = ((unsigned)r1 < 25u) ? r1 : 25;
            const int col = ic * 32 + quad * 8;
#pragma unroll
            for (int bl = 0; bl < 4; ++bl) {
                Bf[bl * 2 + 0] = *(const bf16x8*)&xs[bl * XSZ2 + r0 * XC + col];
                Bf[bl * 2 + 1] = *(const bf16x8*)&xs[bl * XSZ2 + r1 * XC + col];
            }
        };
        auto compute = [&](bf16x8* Ah, bf16x8* Am, bf16x8* Al, bf16x8* Bf) {
#pragma unroll
            for (int pi = 0; pi < 2; ++pi)
#pragma unroll
                for (int nt = 0; nt < 8; ++nt)
                    acc[pi][nt] = MFMA16(Ah[pi], Bf[nt], acc[pi][nt]);
#pragma unroll
            for (int pi = 0; pi < 2; ++pi)
#pragma unroll
                for (int nt = 0; nt < 8; ++nt)
                    acc[pi][nt] = MFMA16(Am[pi], Bf[nt], acc[pi][nt]);
#pragma unroll
            for (int pi = 0; pi < 2; ++pi)
#pragma unroll
                for (int nt = 0; nt < 8; ++nt)
                    acc[pi][nt] = MFMA16(Al[pi], Bf[nt], acc[pi][nt]);
        };

        bf16x8 A0h[2], A0m[2], A0l[2], A1h[2], A1m[2], A1l[2], B0[8], B1[8];
        loadA(0, A0h, A0m, A0l);
        loadB(0, B0);
        for (int n = 0; n < 86; n += 2) {
            loadA(n + 1, A1h, A1m, A1l);
            loadB(n + 1, B1);
            compute(A0h, A0m, A0l, B0);
            loadA(n + 2, A0h, A0m, A0l);
            loadB(n + 2, B0);
            compute(A1h, A1m, A1l, B1);
        }
        loadA(87, A1h, A1m, A1l);
        loadB(87, B1);
        compute(A0h, A0m, A0l, B0);   // n = 86
        compute(A1h, A1m, A1l, B1);   // n = 87
    }

    // ------- conv2 epilogue: BN + LIF, spikes written back into xs -------
#pragma unroll
    for (int bl = 0; bl < 4; ++bl) {
#pragma unroll
        for (int q = 0; q < 4; ++q) {
            __syncthreads();
            if ((w >> 1) == q) {
#pragma unroll
                for (int pi = 0; pi < 2; ++pi)
#pragma unroll
                    for (int th = 0; th < 2; ++th) {
                        int t = th * 16 + lm;
                        if (t < TT) {
                            int ol = (w & 1) * 32 + pi * 16 + quad * 4;
#pragma unroll
                            for (int v = 0; v < 4; ++v)
                                ysq[(ol + v) * 26 + t] = acc[pi][bl * 2 + th][v];
                        }
                    }
            }
            __syncthreads();
            if (tid < 64) {
                const int o = q * 64 + tid;
                float scale = gamma[o] / sqrtf(var[o] + 1e-5f);
                float ofs   = (bias[o] - mean[o]) * scale + beta[o];
                const float* yrow = &ysq[tid * 26];
                unsigned short* sx = (unsigned short*)xs;
                float memv = 0.f;
#pragma unroll
                for (int t = 0; t < TT; ++t) {
                    float a     = yrow[t] * scale + ofs;
                    float reset = (memv > 1.0f) ? 1.0f : 0.f;
                    memv        = 0.95f * memv + a - reset;
                    sx[bl * XSZ2 + t * XC + o] = (memv > 1.0f) ? 0x3F80 : 0;
                }
            }
        }
    }
    __syncthreads();

    // ---------------- conv3 K-loop from LDS (round-9/10 3-acc order) -----
    {
        const int p3  = w >> 2;      // o3-tile
        const int bl3 = w & 3;       // batch
        f32x4 accH[2], accM[2], accL[2];   // [th]
#pragma unroll
        for (int th = 0; th < 2; ++th) {
            accH[th] = (f32x4){0.f, 0.f, 0.f, 0.f};
            accM[th] = (f32x4){0.f, 0.f, 0.f, 0.f};
            accL[th] = (f32x4){0.f, 0.f, 0.f, 0.f};
        }

        auto loadA3 = [&](int n, bf16x8* Ah, bf16x8* Am, bf16x8* Al) {
            n = (n > 87) ? 87 : n;
            const int j = n >> 3, ic = n & 7;
            const size_t kofs =
                ((size_t)(j * 32 + p3 * 16 + lm)) * 256 + ic * 32 + quad * 8;
            *Ah = *(const bf16x8*)(K3hi  + kofs);
            *Am = *(const bf16x8*)(K3mid + kofs);
            *Al = *(const bf16x8*)(K3lo  + kofs);
        };
        auto step3 = [&](int n, bf16x8 Ah, bf16x8 Am, bf16x8 Al) {
            const int j = n >> 3, ic = n & 7;
#pragma unroll
            for (int th = 0; th < 2; ++th) {
                int r = th * 16 + lm + j - 10;
                r = ((unsigned)r < 25u) ? r : 25;
                bf16x8 Bf =
                    *(const bf16x8*)&xs[bl3 * XSZ2 + r * XC + ic * 32 + quad * 8];
                accH[th] = MFMA16(Ah, Bf, accH[th]);
                accM[th] = MFMA16(Am, Bf, accM[th]);
                accL[th] = MFMA16(Al, Bf, accL[th]);
            }
        };

        bf16x8 A0h, A0m, A0l, A1h, A1m, A1l;
        loadA3(0, &A0h, &A0m, &A0l);
        for (int n = 0; n < 86; n += 2) {
            loadA3(n + 1, &A1h, &A1m, &A1l);
            step3(n, A0h, A0m, A0l);
            loadA3(n + 2, &A0h, &A0m, &A0l);
            step3(n + 1, A1h, A1m, A1l);
        }
        loadA3(87, &A1h, &A1m, &A1l);
        step3(86, A0h, A0m, A0l);
        step3(87, A1h, A1m, A1l);

        __syncthreads();   // xs dead; reuse smem as ys3
#pragma unroll
        for (int th = 0; th < 2; ++th) {
            int t = th * 16 + lm;
            if (t < TT) {
#pragma unroll
                for (int v = 0; v < 4; ++v)
                    ys3[(bl3 * 32 + p3 * 16 + quad * 4 + v) * 26 + t] =
                        accH[th][v] + accM[th][v] + accL[th][v];
            }
        }
        __syncthreads();

        if (tid < 80) {
            const int bl2 = tid / 20;
            const int o   = tid % 20;
            float memv = 0.f;
            float bo   = b3[o];
            const float* yrow = &ys3[(bl2 * 32 + o) * 26];
#pragma unroll
            for (int t = 0; t < TT; ++t) {
                float a     = yrow[t] + bo;
                float reset = (memv > 1.0f) ? 1.0f : 0.f;
                memv        = 0.95f * memv + a - reset;
                float spk   = (memv > 1.0f) ? 1.0f : 0.f;
                out[(t * BB + (b0 + bl2)) * 20 + o]               = spk;
                out[TT * BB * 20 + (t * BB + (b0 + bl2)) * 20 + o] = memv;
            }
        }
    }
}

// ---------------------------------------------------------------------------
extern "C" void kernel_launch(void* const* d_in, const int* in_sizes, int n_in,
                              void* d_out, int out_size, void* d_ws, size_t ws_size,
                              hipStream_t stream) {
    const float* data = (const float*)d_in[0];
    const float* W1   = (const float*)d_in[1];
    const float* b1   = (const float*)d_in[2];
    const float* P1   = (const float*)d_in[3];
    const float* SIG1 = (const float*)d_in[4];
    const float* g1   = (const float*)d_in[5];
    const float* be1  = (const float*)d_in[6];
    const float* m1   = (const float*)d_in[7];
    const float* v1   = (const float*)d_in[8];
    const float* W2   = (const float*)d_in[9];
    const float* b2   = (const float*)d_in[10];
    const float* P2   = (const float*)d_in[11];
    const float* SIG2 = (const float*)d_in[12];
    const float* g2   = (const float*)d_in[13];
    const float* be2  = (const float*)d_in[14];
    const float* m2   = (const float*)d_in[15];
    const float* v2   = (const float*)d_in[16];
    const float* W3   = (const float*)d_in[17];
    const float* b3   = (const float*)d_in[18];
    const float* P3   = (const float*)d_in[19];
    const float* SIG3 = (const float*)d_in[20];
    float* out = (float*)d_out;

    // workspace layout (byte offsets, all 16B-aligned)
    char* p = (char*)d_ws;
    __bf16* K1hi  = (__bf16*)p;  p += 901120;    // 11*256*160 bf16
    __bf16* K1mid = (__bf16*)p;  p += 901120;
    __bf16* K1lo  = (__bf16*)p;  p += 901120;
    __bf16* spk1  = (__bf16*)p;  p += 13107200;  // 1024*25*256 bf16
    __bf16* K2hi  = (__bf16*)p;  p += 1441792;   // 11*256*256 bf16
    __bf16* K2mid = (__bf16*)p;  p += 1441792;
    __bf16* K2lo  = (__bf16*)p;  p += 1441792;
    __bf16* K3hi  = (__bf16*)p;  p += 180224;    // 11*32*256 bf16
    __bf16* K3mid = (__bf16*)p;  p += 180224;
    __bf16* K3lo  = (__bf16*)p;

    gen_trip<<<(256 * 160 + 255) / 256, 256, 0, stream>>>(
        W1, P1, SIG1, K1hi, K1mid, K1lo, 256, 256, 140, 160);
    gen_trip<<<(256 * 256 + 255) / 256, 256, 0, stream>>>(
        W2, P2, SIG2, K2hi, K2mid, K2lo, 256, 256, 256, 256);
    gen_trip<<<(32 * 256 + 255) / 256, 256, 0, stream>>>(
        W3, P3, SIG3, K3hi, K3mid, K3lo, 20, 32, 256, 256);

    conv1_mfma<<<BB / 2, 512, 0, stream>>>(data, K1hi, K1mid, K1lo,
                                           b1, g1, be1, m1, v1, spk1);
    conv23_mfma<<<BB / 4, 512, 0, stream>>>(spk1, K2hi, K2mid, K2lo,
                                            b2, g2, be2, m2, v2,
                                            K3hi, K3mid, K3lo, b3, out);
}